// Round 1
// baseline (281.519 us; speedup 1.0000x reference)
//
#include <hip/hip_runtime.h>
#include <math.h>

#define DIM   2048
#define NEXP  64
#define NGRP  8
#define GSIZE 8
#define TOPK  8
#define TOPKG 4

#define TPB1  1024
#define NKS   8              // K-slices per block (one per wave-pair group)
#define KSL   (DIM / NKS)    // 256 k per slice
#define SMSTR 1092           // 16*68+4 floats: bank-rotating k-slice stride

// margin thresholds (fp32 score scale). bf16-split GEMM logit error ~5e-6
// (dropped lo*lo 2^-18/term + fp32 MFMA accum) -> ~1.3e-6 score; ref ~3e-7.
// TAU ~ 30x the 5-sigma combined error. Expected flag rate ~4%.
#define TAU_E 6e-5f
#define TAU_G 1.2e-4f
#define NEG_INF (-3.4e38f)
#define WLOFF 16
#define WT_OFF (1 << 18)     // Wf at d_ws + 256 KB (512 KB of packed B-frags)

typedef __attribute__((ext_vector_type(8)))  short bf16x8;   // 8 bf16 (4 VGPR)
typedef __attribute__((ext_vector_type(16))) float f32x16;   // 32x32 C/D

union FragU { bf16x8 v; unsigned short u[8]; };

static __device__ __forceinline__ unsigned short bf16_rne(float f) {
    unsigned u = __builtin_bit_cast(unsigned, f);
    u += 0x7FFFu + ((u >> 16) & 1u);
    return (unsigned short)(u >> 16);
}
static __device__ __forceinline__ float bf16_to_f(unsigned short h) {
    unsigned u = ((unsigned)h) << 16;
    return __builtin_bit_cast(float, u);
}

// ---- kernel 0: pack W into B-fragment layout (hi/lo bf16) + zero worklist --
// B-frag for mfma_f32_32x32x16_bf16: B[k][n], n = lane&31, k = (lane>>5)*8+j.
// Wf element index: (((h*2 + n2)*128 + kc)*64 + lane)*8 + j   (ushorts)
__global__ __launch_bounds__(256) void prep_kernel(
    const float* __restrict__ W, unsigned short* __restrict__ Wf,
    int* __restrict__ wl)
{
    const int g = blockIdx.x * 256 + threadIdx.x;   // 0..131071
    const int e = g >> 11, k = g & 2047;
    const float w = W[g];                            // W[e][k], coalesced
    const unsigned short hi = bf16_rne(w);
    const unsigned short lo = bf16_rne(w - bf16_to_f(hi));
    const int n2 = e >> 5, lcol = e & 31;
    const int kc = k >> 4, khalf = (k >> 3) & 1, j = k & 7;
    const int lane = (khalf << 5) | lcol;
    Wf[((((0 * 2 + n2) * 128 + kc) << 6) + lane) * 8 + j] = hi;
    Wf[((((1 * 2 + n2) * 128 + kc) << 6) + lane) * 8 + j] = lo;
    if (g < WLOFF) wl[g] = 0;
}

// ---- kernel 1: bf16-split MFMA GEMM + merge + routing + margin flag -------
// Register-pipelined: B-frags double-buffered, x triple-buffered, 16 fully
// unrolled K-chunk steps. Issue order per step: [MFMA B[t]] then B[t+2] loads
// then x[t+3] loads, so the compiler's counted vmcnt for B[t] (8 newer loads
// outstanding) never drains the x prefetch queue. Numerically bit-identical
// to the unpipelined version (same values, same op order).
__global__ __launch_bounds__(TPB1, 4) void gate_kernel(
    const float* __restrict__ x,
    const unsigned short* __restrict__ Wf,
    const float* __restrict__ b,
    const float* __restrict__ bias,
    float* __restrict__ out_w,
    float* __restrict__ out_i,
    int* __restrict__ wl)
{
    __shared__ float sM[NKS * SMSTR];    // 34.9 KB merge buffer
    __shared__ float sS[64][65];         // 16.6 KB score table

    const int tid  = threadIdx.x;
    const int w    = tid >> 6;
    const int lane = tid & 63;
    const int m    = w >> 3;             // M-tile: tokens [32m, 32m+32)
    const int ks   = w & 7;              // K-slice: k in [256ks, 256ks+256)
    const int tok0 = blockIdx.x * 64;
    const int l31  = lane & 31, lh = lane >> 5;

    // A operand: A[row = lane&31][k-run = (lane>>5)*8 + j]
    const float* xr = x + (size_t)(tok0 + 32 * m + l31) * DIM + ks * KSL + lh * 8;
    const bf16x8* Wfv = (const bf16x8*)Wf;   // 16 B per element
    const int kc0 = ks * 16;

    f32x16 acc0, acc1;
#pragma unroll
    for (int z = 0; z < 16; ++z) { acc0[z] = 0.f; acc1[z] = 0.f; }

    // ---- pipeline prologue: x[0], B[0], B[1], x[1], x[2] (this issue order
    // keeps B[0]'s first-use wait from draining the deeper x prefetches) ----
    float4 xA[3], xB[3];
    bf16x8 Bh0[2], Bh1[2], Bl0[2], Bl1[2];

    xA[0] = *(const float4*)(xr + 0);
    xB[0] = *(const float4*)(xr + 4);
    Bh0[0] = Wfv[((0 * 2 + 0) * 128 + kc0 + 0) * 64 + lane];
    Bh1[0] = Wfv[((0 * 2 + 1) * 128 + kc0 + 0) * 64 + lane];
    Bl0[0] = Wfv[((1 * 2 + 0) * 128 + kc0 + 0) * 64 + lane];
    Bl1[0] = Wfv[((1 * 2 + 1) * 128 + kc0 + 0) * 64 + lane];
    Bh0[1] = Wfv[((0 * 2 + 0) * 128 + kc0 + 1) * 64 + lane];
    Bh1[1] = Wfv[((0 * 2 + 1) * 128 + kc0 + 1) * 64 + lane];
    Bl0[1] = Wfv[((1 * 2 + 0) * 128 + kc0 + 1) * 64 + lane];
    Bl1[1] = Wfv[((1 * 2 + 1) * 128 + kc0 + 1) * 64 + lane];
    xA[1] = *(const float4*)(xr + 16);
    xB[1] = *(const float4*)(xr + 20);
    xA[2] = *(const float4*)(xr + 32);
    xB[2] = *(const float4*)(xr + 36);

#pragma unroll
    for (int t = 0; t < 16; ++t) {       // one K=16 chunk per step
        const int xs = t % 3;            // x ring slot (compile-time)
        const int bs = t & 1;            // B ring slot (compile-time)

        // 1. convert x[t] (already in registers / oldest outstanding)
        const float4 qa = xA[xs], qb = xB[xs];
        const float xv[8] = {qa.x, qa.y, qa.z, qa.w, qb.x, qb.y, qb.z, qb.w};
        FragU ah, al;
#pragma unroll
        for (int j = 0; j < 8; ++j) {
            const unsigned short h = bf16_rne(xv[j]);
            ah.u[j] = (short)h;
            al.u[j] = (short)bf16_rne(xv[j] - bf16_to_f(h));
        }

        // 2. MFMA with B[t] (8 newer loads outstanding -> vmcnt(8), x stays)
        acc0 = __builtin_amdgcn_mfma_f32_32x32x16_bf16(ah.v, Bh0[bs], acc0, 0, 0, 0);
        acc0 = __builtin_amdgcn_mfma_f32_32x32x16_bf16(ah.v, Bl0[bs], acc0, 0, 0, 0);
        acc0 = __builtin_amdgcn_mfma_f32_32x32x16_bf16(al.v, Bh0[bs], acc0, 0, 0, 0);
        acc1 = __builtin_amdgcn_mfma_f32_32x32x16_bf16(ah.v, Bh1[bs], acc1, 0, 0, 0);
        acc1 = __builtin_amdgcn_mfma_f32_32x32x16_bf16(ah.v, Bl1[bs], acc1, 0, 0, 0);
        acc1 = __builtin_amdgcn_mfma_f32_32x32x16_bf16(al.v, Bh1[bs], acc1, 0, 0, 0);

        // 3. prefetch B[t+2] into the slot just consumed (L2-hot, ~2 steps cover)
        if (t + 2 < 16) {
            const int kc = kc0 + t + 2;
            Bh0[bs] = Wfv[((0 * 2 + 0) * 128 + kc) * 64 + lane];
            Bh1[bs] = Wfv[((0 * 2 + 1) * 128 + kc) * 64 + lane];
            Bl0[bs] = Wfv[((1 * 2 + 0) * 128 + kc) * 64 + lane];
            Bl1[bs] = Wfv[((1 * 2 + 1) * 128 + kc) * 64 + lane];
        }
        // 4. prefetch x[t+3] into the slot freed by step 1 (HBM, ~3 steps cover)
        if (t + 3 < 16) {
            xA[xs] = *(const float4*)(xr + 16 * (t + 3));
            xB[xs] = *(const float4*)(xr + 16 * (t + 3) + 4);
        }
    }

    // ---- merge 8 K-slice partials (4 rounds x 16 tokens), fused sigmoid ----
    // C/D layout (m74/m101-verified): col = lane&31, row = (reg&3)+8*(reg>>2)+4*(lane>>5)
#pragma unroll
    for (int r = 0; r < 4; ++r) {
#pragma unroll
        for (int jj = 0; jj < 4; ++jj) {
            const int t16 = 8 * m + jj + 4 * lh;       // row-in-round
            sM[ks * SMSTR + t16 * 68 + l31]      = acc0[4 * r + jj];
            sM[ks * SMSTR + t16 * 68 + l31 + 32] = acc1[4 * r + jj];
        }
        __syncthreads();
        {
            const int t16 = tid >> 6;                  // 0..15
            const int e   = tid & 63;
            float sum = 0.f;
#pragma unroll
            for (int s = 0; s < NKS; ++s)
                sum += sM[s * SMSTR + t16 * 68 + e];   // ordered, deterministic
            const float logit = sum + b[e];
            const float wv = 1.0f / (1.0f + expf(-logit));
            const int t_blk = 32 * (t16 >> 3) + 8 * r + (t16 & 7);
            sS[t_blk][e] = wv + bias[e];
        }
        __syncthreads();
    }

    // ---- routing + margin flagging: thread t per token (r6-verified) ----
    if (tid < 64) {
        const int t = tid;

        float gs[NGRP];
#pragma unroll
        for (int g = 0; g < NGRP; ++g) {
            float m1 = NEG_INF, m2 = NEG_INF;
#pragma unroll
            for (int j = 0; j < GSIZE; ++j) {
                const float v = sS[t][g * GSIZE + j];
                if (v > m1) { m2 = m1; m1 = v; }
                else if (v > m2) { m2 = v; }
            }
            gs[g] = m1 + m2;
        }

        unsigned gmask = 0u;
        float g4val = NEG_INF;
        for (int rr = 0; rr < TOPKG; ++rr) {
            float best = NEG_INF; int bi = 0;
#pragma unroll
            for (int g = 0; g < NGRP; ++g) {
                const float v = ((gmask >> g) & 1u) ? NEG_INF : gs[g];
                if (v > best) { best = v; bi = g; }
            }
            gmask |= 1u << bi;
            g4val = best;
        }
        float m5 = NEG_INF;
#pragma unroll
        for (int g = 0; g < NGRP; ++g)
            if (!((gmask >> g) & 1u) && gs[g] > m5) m5 = gs[g];
        const float margin_g = g4val - m5;

        unsigned long long chosen = 0ull;
        const size_t obase = (size_t)(tok0 + t) * TOPK;
        float vals[TOPK + 1];
        for (int rr = 0; rr < TOPK + 1; ++rr) {
            float best = NEG_INF; int bi = 0;
            for (int e = 0; e < NEXP; ++e) {
                float v = ((gmask >> (e >> 3)) & 1u) ? sS[t][e] : 0.0f;
                if ((chosen >> e) & 1ull) v = NEG_INF;
                if (v > best) { best = v; bi = e; }
            }
            vals[rr] = best;
            if (rr < TOPK) {
                chosen |= 1ull << (unsigned)bi;
                out_w[obase + rr] = ((gmask >> (bi >> 3)) & 1u)
                                  ? (sS[t][bi] - bias[bi]) : 0.0f;
                out_i[obase + rr] = (float)bi;
            }
        }
        float margin_e = 1e30f;
#pragma unroll
        for (int rr = 0; rr < TOPK; ++rr) {
            const float d = vals[rr] - vals[rr + 1];
            if (d < margin_e) margin_e = d;
        }

        if (margin_g < TAU_G || margin_e < TAU_E) {
            const int slot = atomicAdd(wl, 1);
            wl[WLOFF + slot] = tok0 + t;
        }
    }
}

// ---------------- kernel 2: fp64 exact fixup, 1 token per iteration ---------
__global__ __launch_bounds__(256) void gate_fix_kernel(
    const float* __restrict__ x,
    const float* __restrict__ W,
    const float* __restrict__ b,
    const float* __restrict__ bias,
    float* __restrict__ out_w,
    float* __restrict__ out_i,
    const int* __restrict__ wl)
{
    const int count = wl[0];

    __shared__ __align__(16) float sX[DIM];
    __shared__ double sPart[NEXP][4];
    __shared__ float  sS2[NEXP], sW2[NEXP];

    const int tid = threadIdx.x;
    const int e   = tid >> 2;
    const int s   = tid & 3;

    for (int widx = blockIdx.x; widx < count; widx += (int)gridDim.x) {
        const int tok = wl[WLOFF + widx];

        const float4* xr = (const float4*)(x + (size_t)tok * DIM);
        ((float4*)sX)[tid]       = xr[tid];
        ((float4*)sX)[tid + 256] = xr[tid + 256];
        __syncthreads();

        const float4* Wr = (const float4*)(W + (size_t)e * DIM);
        double a0 = 0., a1 = 0., a2 = 0., a3 = 0.;
#pragma unroll 8
        for (int mm = 0; mm < DIM / 16; ++mm) {
            const int c = mm * 4 + s;
            const float4 wv = Wr[c];
            const float4 xv = ((const float4*)sX)[c];
            a0 = fma((double)xv.x, (double)wv.x, a0);
            a1 = fma((double)xv.y, (double)wv.y, a1);
            a2 = fma((double)xv.z, (double)wv.z, a2);
            a3 = fma((double)xv.w, (double)wv.w, a3);
        }
        sPart[e][s] = (a0 + a1) + (a2 + a3);
        __syncthreads();

        if (tid < NEXP) {
            const double logit = ((sPart[tid][0] + sPart[tid][1])
                                + (sPart[tid][2] + sPart[tid][3])) + (double)b[tid];
            const float wv = (float)(1.0 / (1.0 + exp(-logit)));
            sW2[tid] = wv;
            sS2[tid] = wv + bias[tid];
        }
        __syncthreads();

        if (tid == 0) {
            float gs[NGRP];
#pragma unroll
            for (int g = 0; g < NGRP; ++g) {
                float m1 = NEG_INF, m2 = NEG_INF;
#pragma unroll
                for (int j = 0; j < GSIZE; ++j) {
                    const float v = sS2[g * GSIZE + j];
                    if (v > m1) { m2 = m1; m1 = v; }
                    else if (v > m2) { m2 = v; }
                }
                gs[g] = m1 + m2;
            }
            unsigned gmask = 0u;
            for (int rr = 0; rr < TOPKG; ++rr) {
                float best = NEG_INF; int bi = 0;
#pragma unroll
                for (int g = 0; g < NGRP; ++g) {
                    const float v = ((gmask >> g) & 1u) ? NEG_INF : gs[g];
                    if (v > best) { best = v; bi = g; }
                }
                gmask |= 1u << bi;
            }
            unsigned long long chosen = 0ull;
            const size_t obase = (size_t)tok * TOPK;
            for (int rr = 0; rr < TOPK; ++rr) {
                float best = NEG_INF; int bi = 0;
                for (int e2 = 0; e2 < NEXP; ++e2) {
                    float v = ((gmask >> (e2 >> 3)) & 1u) ? sS2[e2] : 0.0f;
                    if ((chosen >> e2) & 1ull) v = NEG_INF;
                    if (v > best) { best = v; bi = e2; }
                }
                chosen |= 1ull << (unsigned)bi;
                out_w[obase + rr] = ((gmask >> (bi >> 3)) & 1u) ? sW2[bi] : 0.0f;
                out_i[obase + rr] = (float)bi;
            }
        }
        __syncthreads();
    }
}

extern "C" void kernel_launch(void* const* d_in, const int* in_sizes, int n_in,
                              void* d_out, int out_size, void* d_ws, size_t ws_size,
                              hipStream_t stream) {
    const float* x    = (const float*)d_in[0];
    const float* W    = (const float*)d_in[1];
    const float* b    = (const float*)d_in[2];
    const float* bias = (const float*)d_in[3];

    const int n = in_sizes[0] / DIM;   // 16384 tokens
    float* out_w = (float*)d_out;
    float* out_i = out_w + (size_t)n * TOPK;
    int*   wl    = (int*)d_ws;
    unsigned short* Wf = (unsigned short*)((char*)d_ws + WT_OFF);

    prep_kernel<<<dim3((NEXP * DIM) / 256), dim3(256), 0, stream>>>(W, Wf, wl);
    gate_kernel<<<dim3(n / 64), dim3(TPB1), 0, stream>>>(
        x, Wf, b, bias, out_w, out_i, wl);
    gate_fix_kernel<<<dim3(1024), dim3(256), 0, stream>>>(
        x, W, b, bias, out_w, out_i, wl);
}

// Round 2
// 274.265 us; speedup vs baseline: 1.0264x; 1.0264x over previous
//
#include <hip/hip_runtime.h>
#include <math.h>

#define DIM   2048
#define NEXP  64
#define NGRP  8
#define GSIZE 8
#define TOPK  8
#define TOPKG 4

#define TPB1  1024
#define NKS   8              // K-slices per block (one per wave-pair group)
#define KSL   (DIM / NKS)    // 256 k per slice
#define SMSTR 1092           // 16*68+4 floats: bank-rotating k-slice stride

// margin thresholds (fp32 score scale). f16-split GEMM logit error <= the
// old bf16-split's ~5e-6 (residual-corrected RTZ split; fp32 MFMA accum
// dominates) -> keep TAU unchanged; expected flag rate ~4%.
#define TAU_E 6e-5f
#define TAU_G 1.2e-4f
#define NEG_INF (-3.4e38f)
#define WLOFF 16
#define WT_OFF (1 << 18)     // Wf at d_ws + 256 KB (512 KB of packed B-frags)

typedef __attribute__((ext_vector_type(8)))  _Float16 f16x8;  // 8 f16 (4 VGPR)
typedef __attribute__((ext_vector_type(16))) float    f32x16; // 32x32 C/D

#define SB() __builtin_amdgcn_sched_barrier(0)
#define WAITVM(n) asm volatile("s_waitcnt vmcnt(" #n ")" ::: "memory")

static __device__ __forceinline__ void gload_lds16(const void* g, void* l) {
    __builtin_amdgcn_global_load_lds(
        (const __attribute__((address_space(1))) unsigned*)g,
        (__attribute__((address_space(3))) unsigned*)l,
        16, 0, 0);
}

// ---- kernel 0: pack W into B-fragment layout (hi/lo f16) + zero worklist --
// B-frag for mfma_f32_32x32x16_f16: B[k][n], n = lane&31, k = (lane>>5)*8+j.
// Wf element index: (((h*2 + n2)*128 + kc)*64 + lane)*8 + j   (ushorts)
__global__ __launch_bounds__(256) void prep_kernel(
    const float* __restrict__ W, unsigned short* __restrict__ Wf,
    int* __restrict__ wl)
{
    const int g = blockIdx.x * 256 + threadIdx.x;   // 0..131071
    const int e = g >> 11, k = g & 2047;
    const float w = W[g];                            // W[e][k], coalesced
    const _Float16 hi = (_Float16)w;                 // RNE
    const _Float16 lo = (_Float16)(w - (float)hi);   // exact residual, RNE
    const int n2 = e >> 5, lcol = e & 31;
    const int kc = k >> 4, khalf = (k >> 3) & 1, j = k & 7;
    const int lane = (khalf << 5) | lcol;
    Wf[((((0 * 2 + n2) * 128 + kc) << 6) + lane) * 8 + j] =
        __builtin_bit_cast(unsigned short, hi);
    Wf[((((1 * 2 + n2) * 128 + kc) << 6) + lane) * 8 + j] =
        __builtin_bit_cast(unsigned short, lo);
    if (g < WLOFF) wl[g] = 0;
}

// ---- kernel 1: f16-split MFMA GEMM + merge + routing + margin flag --------
// Structural pipeline (m201/T3+T4 pattern): B-frags double-buffered in LDS
// via global_load_lds (fire-and-forget, staged once per ks by the m=0 wave,
// read by both m-waves), counted s_waitcnt vmcnt asm, raw s_barrier,
// sched_barrier(0) fences pinning issue order. x in a 3-deep VGPR ring
// issued 2 phases ahead. Per-block K-chunk stagger (roff) decorrelates the
// blocks' Wf line accesses in L2. Accumulation order is deterministic per
// block (rotation only); error scale unchanged -> TAU/fixup unchanged.
__global__ __launch_bounds__(TPB1, 4) void gate_kernel(
    const float* __restrict__ x,
    const unsigned short* __restrict__ Wf,
    const float* __restrict__ b,
    const float* __restrict__ bias,
    float* __restrict__ out_w,
    float* __restrict__ out_i,
    int* __restrict__ wl)
{
    // union: [0,64K) B staging (2 buf x 8 ks x 4 KB) during GEMM;
    // reused as sM (34944 B) + sS (16640 B) for merge/routing after.
    __shared__ __align__(16) char sLDS[65536];
    float* sM = (float*)sLDS;
    float (*sS)[65] = (float (*)[65])(sLDS + 34944);

    const int tid  = threadIdx.x;
    const int w    = tid >> 6;
    const int lane = tid & 63;
    const int m    = w >> 3;             // M-tile: tokens [32m, 32m+32)
    const int ks   = w & 7;              // K-slice: k in [256ks, 256ks+256)
    const int tok0 = blockIdx.x * 64;
    const int l31  = lane & 31, lh = lane >> 5;
    const int roff = (blockIdx.x >> 3) & 15;   // chunk stagger

    // A operand: A[row = lane&31][k-run = (lane>>5)*8 + j]
    const float* xr = x + (size_t)(tok0 + 32 * m + l31) * DIM + ks * KSL + lh * 8;
    const char* Wfb = (const char*)Wf;

    f32x16 acc0, acc1;
#pragma unroll
    for (int z = 0; z < 16; ++z) { acc0[z] = 0.f; acc1[z] = 0.f; }

    // stage B chunk tt (4 frags x 1 KB) into buf (tt&1) for this ks
#define STAGE_B(tt, cc) do {                                                  \
        char* dst_ = sLDS + (((tt) & 1) ? 32768 : 0) + ks * 4096;             \
        const int kc_ = ks * 16 + (cc);                                       \
        gload_lds16(Wfb + (size_t)((0 * 128 + kc_) * 64 + lane) * 16, dst_);  \
        gload_lds16(Wfb + (size_t)((1 * 128 + kc_) * 64 + lane) * 16, dst_ + 1024); \
        gload_lds16(Wfb + (size_t)((2 * 128 + kc_) * 64 + lane) * 16, dst_ + 2048); \
        gload_lds16(Wfb + (size_t)((3 * 128 + kc_) * 64 + lane) * 16, dst_ + 3072); \
    } while (0)

    // ---- prologue: x(0); B(0); x(1)  (order pinned for vmcnt counting) ----
    float4 pA[3], pB[3];
    {
        const int cc0 = roff;
        pA[0] = *(const float4*)(xr + cc0 * 16);
        pB[0] = *(const float4*)(xr + cc0 * 16 + 4);
        SB();
        if (m == 0) STAGE_B(0, cc0);
        SB();
        const int cc1 = (1 + roff) & 15;
        pA[1] = *(const float4*)(xr + cc1 * 16);
        pB[1] = *(const float4*)(xr + cc1 * 16 + 4);
        SB();
    }

#pragma unroll
    for (int t = 0; t < 16; ++t) {
        // 1. issue next B stage (m0 waves): +4 vm ops
        if (t + 1 < 16) {
            const int cc1 = (t + 1 + roff) & 15;
            if (m == 0) STAGE_B(t + 1, cc1);
        }
        SB();
        // 2. issue x prefetch 2 ahead: +2 vm ops
        if (t + 2 < 16) {
            const int cc2 = (t + 2 + roff) & 15;
            pA[(t + 2) % 3] = *(const float4*)(xr + cc2 * 16);
            pB[(t + 2) % 3] = *(const float4*)(xr + cc2 * 16 + 4);
        }
        // 3. counted wait: retire through B(t) (m0: 8 newer ops in flight;
        //    m1 waves: no-op, compiler inserts its own x wait at use)
        if (t <= 13)      WAITVM(8);
        else if (t == 14) WAITVM(6);
        else              WAITVM(0);
        SB();
        __builtin_amdgcn_s_barrier();   // B(t) visible to both m-waves
        SB();

        // 4. compute chunk t: 4 ds_read_b128 (B) + cvt_pkrtz split + 6 MFMA
        const char* src = sLDS + ((t & 1) ? 32768 : 0) + ks * 4096;
        const f16x8 bh0 = *(const f16x8*)(src + 0 * 1024 + lane * 16);
        const f16x8 bh1 = *(const f16x8*)(src + 1 * 1024 + lane * 16);
        const f16x8 bl0 = *(const f16x8*)(src + 2 * 1024 + lane * 16);
        const f16x8 bl1 = *(const f16x8*)(src + 3 * 1024 + lane * 16);
        const float4 qa = pA[t % 3], qb = pB[t % 3];
        const float xv[8] = {qa.x, qa.y, qa.z, qa.w, qb.x, qb.y, qb.z, qb.w};
        f16x8 ah, al;
#pragma unroll
        for (int j = 0; j < 8; j += 2) {
            const auto h2 = __builtin_amdgcn_cvt_pkrtz(xv[j], xv[j + 1]);
            const auto l2 = __builtin_amdgcn_cvt_pkrtz(xv[j]     - (float)h2.x,
                                                       xv[j + 1] - (float)h2.y);
            ah[j] = h2.x; ah[j + 1] = h2.y;
            al[j] = l2.x; al[j + 1] = l2.y;
        }
        acc0 = __builtin_amdgcn_mfma_f32_32x32x16_f16(ah, bh0, acc0, 0, 0, 0);
        acc0 = __builtin_amdgcn_mfma_f32_32x32x16_f16(ah, bl0, acc0, 0, 0, 0);
        acc0 = __builtin_amdgcn_mfma_f32_32x32x16_f16(al, bh0, acc0, 0, 0, 0);
        acc1 = __builtin_amdgcn_mfma_f32_32x32x16_f16(ah, bh1, acc1, 0, 0, 0);
        acc1 = __builtin_amdgcn_mfma_f32_32x32x16_f16(ah, bl1, acc1, 0, 0, 0);
        acc1 = __builtin_amdgcn_mfma_f32_32x32x16_f16(al, bh1, acc1, 0, 0, 0);
        SB();
        __builtin_amdgcn_s_barrier();   // protect buf (t&1) before re-stage
        SB();
    }
#undef STAGE_B

    // ---- merge 8 K-slice partials (4 rounds x 16 tokens), fused sigmoid ----
    // C/D layout (m74/m101-verified): col = lane&31, row = (reg&3)+8*(reg>>2)+4*(lane>>5)
#pragma unroll
    for (int r = 0; r < 4; ++r) {
#pragma unroll
        for (int jj = 0; jj < 4; ++jj) {
            const int t16 = 8 * m + jj + 4 * lh;       // row-in-round
            sM[ks * SMSTR + t16 * 68 + l31]      = acc0[4 * r + jj];
            sM[ks * SMSTR + t16 * 68 + l31 + 32] = acc1[4 * r + jj];
        }
        __syncthreads();
        {
            const int t16 = tid >> 6;                  // 0..15
            const int e   = tid & 63;
            float sum = 0.f;
#pragma unroll
            for (int s = 0; s < NKS; ++s)
                sum += sM[s * SMSTR + t16 * 68 + e];   // ordered, deterministic
            const float logit = sum + b[e];
            const float wv = 1.0f / (1.0f + expf(-logit));
            const int t_blk = 32 * (t16 >> 3) + 8 * r + (t16 & 7);
            sS[t_blk][e] = wv + bias[e];
        }
        __syncthreads();
    }

    // ---- routing + margin flagging: thread t per token (r6-verified) ----
    if (tid < 64) {
        const int t = tid;

        float gs[NGRP];
#pragma unroll
        for (int g = 0; g < NGRP; ++g) {
            float m1 = NEG_INF, m2 = NEG_INF;
#pragma unroll
            for (int j = 0; j < GSIZE; ++j) {
                const float v = sS[t][g * GSIZE + j];
                if (v > m1) { m2 = m1; m1 = v; }
                else if (v > m2) { m2 = v; }
            }
            gs[g] = m1 + m2;
        }

        unsigned gmask = 0u;
        float g4val = NEG_INF;
        for (int rr = 0; rr < TOPKG; ++rr) {
            float best = NEG_INF; int bi = 0;
#pragma unroll
            for (int g = 0; g < NGRP; ++g) {
                const float v = ((gmask >> g) & 1u) ? NEG_INF : gs[g];
                if (v > best) { best = v; bi = g; }
            }
            gmask |= 1u << bi;
            g4val = best;
        }
        float m5 = NEG_INF;
#pragma unroll
        for (int g = 0; g < NGRP; ++g)
            if (!((gmask >> g) & 1u) && gs[g] > m5) m5 = gs[g];
        const float margin_g = g4val - m5;

        unsigned long long chosen = 0ull;
        const size_t obase = (size_t)(tok0 + t) * TOPK;
        float vals[TOPK + 1];
        for (int rr = 0; rr < TOPK + 1; ++rr) {
            float best = NEG_INF; int bi = 0;
            for (int e = 0; e < NEXP; ++e) {
                float v = ((gmask >> (e >> 3)) & 1u) ? sS[t][e] : 0.0f;
                if ((chosen >> e) & 1ull) v = NEG_INF;
                if (v > best) { best = v; bi = e; }
            }
            vals[rr] = best;
            if (rr < TOPK) {
                chosen |= 1ull << (unsigned)bi;
                out_w[obase + rr] = ((gmask >> (bi >> 3)) & 1u)
                                  ? (sS[t][bi] - bias[bi]) : 0.0f;
                out_i[obase + rr] = (float)bi;
            }
        }
        float margin_e = 1e30f;
#pragma unroll
        for (int rr = 0; rr < TOPK; ++rr) {
            const float d = vals[rr] - vals[rr + 1];
            if (d < margin_e) margin_e = d;
        }

        if (margin_g < TAU_G || margin_e < TAU_E) {
            const int slot = atomicAdd(wl, 1);
            wl[WLOFF + slot] = tok0 + t;
        }
    }
}

// ---------------- kernel 2: fp64 exact fixup, 1 token per iteration ---------
__global__ __launch_bounds__(256) void gate_fix_kernel(
    const float* __restrict__ x,
    const float* __restrict__ W,
    const float* __restrict__ b,
    const float* __restrict__ bias,
    float* __restrict__ out_w,
    float* __restrict__ out_i,
    const int* __restrict__ wl)
{
    const int count = wl[0];

    __shared__ __align__(16) float sX[DIM];
    __shared__ double sPart[NEXP][4];
    __shared__ float  sS2[NEXP], sW2[NEXP];

    const int tid = threadIdx.x;
    const int e   = tid >> 2;
    const int s   = tid & 3;

    for (int widx = blockIdx.x; widx < count; widx += (int)gridDim.x) {
        const int tok = wl[WLOFF + widx];

        const float4* xr = (const float4*)(x + (size_t)tok * DIM);
        ((float4*)sX)[tid]       = xr[tid];
        ((float4*)sX)[tid + 256] = xr[tid + 256];
        __syncthreads();

        const float4* Wr = (const float4*)(W + (size_t)e * DIM);
        double a0 = 0., a1 = 0., a2 = 0., a3 = 0.;
#pragma unroll 8
        for (int mm = 0; mm < DIM / 16; ++mm) {
            const int c = mm * 4 + s;
            const float4 wv = Wr[c];
            const float4 xv = ((const float4*)sX)[c];
            a0 = fma((double)xv.x, (double)wv.x, a0);
            a1 = fma((double)xv.y, (double)wv.y, a1);
            a2 = fma((double)xv.z, (double)wv.z, a2);
            a3 = fma((double)xv.w, (double)wv.w, a3);
        }
        sPart[e][s] = (a0 + a1) + (a2 + a3);
        __syncthreads();

        if (tid < NEXP) {
            const double logit = ((sPart[tid][0] + sPart[tid][1])
                                + (sPart[tid][2] + sPart[tid][3])) + (double)b[tid];
            const float wv = (float)(1.0 / (1.0 + exp(-logit)));
            sW2[tid] = wv;
            sS2[tid] = wv + bias[tid];
        }
        __syncthreads();

        if (tid == 0) {
            float gs[NGRP];
#pragma unroll
            for (int g = 0; g < NGRP; ++g) {
                float m1 = NEG_INF, m2 = NEG_INF;
#pragma unroll
                for (int j = 0; j < GSIZE; ++j) {
                    const float v = sS2[g * GSIZE + j];
                    if (v > m1) { m2 = m1; m1 = v; }
                    else if (v > m2) { m2 = v; }
                }
                gs[g] = m1 + m2;
            }
            unsigned gmask = 0u;
            for (int rr = 0; rr < TOPKG; ++rr) {
                float best = NEG_INF; int bi = 0;
#pragma unroll
                for (int g = 0; g < NGRP; ++g) {
                    const float v = ((gmask >> g) & 1u) ? NEG_INF : gs[g];
                    if (v > best) { best = v; bi = g; }
                }
                gmask |= 1u << bi;
            }
            unsigned long long chosen = 0ull;
            const size_t obase = (size_t)tok * TOPK;
            for (int rr = 0; rr < TOPK; ++rr) {
                float best = NEG_INF; int bi = 0;
                for (int e2 = 0; e2 < NEXP; ++e2) {
                    float v = ((gmask >> (e2 >> 3)) & 1u) ? sS2[e2] : 0.0f;
                    if ((chosen >> e2) & 1ull) v = NEG_INF;
                    if (v > best) { best = v; bi = e2; }
                }
                chosen |= 1ull << (unsigned)bi;
                out_w[obase + rr] = ((gmask >> (bi >> 3)) & 1u) ? sW2[bi] : 0.0f;
                out_i[obase + rr] = (float)bi;
            }
        }
        __syncthreads();
    }
}

extern "C" void kernel_launch(void* const* d_in, const int* in_sizes, int n_in,
                              void* d_out, int out_size, void* d_ws, size_t ws_size,
                              hipStream_t stream) {
    const float* x    = (const float*)d_in[0];
    const float* W    = (const float*)d_in[1];
    const float* b    = (const float*)d_in[2];
    const float* bias = (const float*)d_in[3];

    const int n = in_sizes[0] / DIM;   // 16384 tokens
    float* out_w = (float*)d_out;
    float* out_i = out_w + (size_t)n * TOPK;
    int*   wl    = (int*)d_ws;
    unsigned short* Wf = (unsigned short*)((char*)d_ws + WT_OFF);

    prep_kernel<<<dim3((NEXP * DIM) / 256), dim3(256), 0, stream>>>(W, Wf, wl);
    gate_kernel<<<dim3(n / 64), dim3(TPB1), 0, stream>>>(
        x, Wf, b, bias, out_w, out_i, wl);
    gate_fix_kernel<<<dim3(1024), dim3(256), 0, stream>>>(
        x, W, b, bias, out_w, out_i, wl);
}

// Round 3
// 270.976 us; speedup vs baseline: 1.0389x; 1.0121x over previous
//
#include <hip/hip_runtime.h>
#include <math.h>

#define DIM   2048
#define NEXP  64
#define NGRP  8
#define GSIZE 8
#define TOPK  8
#define TOPKG 4

#define TPB1  1024
#define NKS   8              // K-slices (one per wave with m-pair), merge width
#define SMSTR 1092           // 16*68+4 floats: bank-rotating k-slice stride

// margin thresholds (fp32 score scale). f16-split GEMM logit error ~5e-6;
// TAU ~ 30x the 5-sigma combined error. Expected flag rate ~4%.
#define TAU_E 6e-5f
#define TAU_G 1.2e-4f
#define NEG_INF (-3.4e38f)
#define WLOFF 16
#define WT_OFF (1 << 18)     // Wf at d_ws + 256 KB (512 KB of packed B-frags)

typedef __attribute__((ext_vector_type(8)))  _Float16 f16x8;  // 8 f16 (4 VGPR)
typedef __attribute__((ext_vector_type(16))) float    f32x16; // 32x32 C/D

#define SB() __builtin_amdgcn_sched_barrier(0)
#define WAITVM(n) asm volatile("s_waitcnt vmcnt(" #n ")" ::: "memory")

static __device__ __forceinline__ void gload_lds16(const void* g, void* l) {
    __builtin_amdgcn_global_load_lds(
        (const __attribute__((address_space(1))) unsigned*)g,
        (__attribute__((address_space(3))) unsigned*)l,
        16, 0, 0);
}

// ---- kernel 0: pack W into B-fragment layout (hi/lo f16) + zero worklist --
// B-frag for mfma_f32_32x32x16_f16: B[k][n], n = lane&31, k = (lane>>5)*8+j.
// Wf element index: (((h*2 + n2)*128 + kc)*64 + lane)*8 + j   (ushorts)
__global__ __launch_bounds__(256) void prep_kernel(
    const float* __restrict__ W, unsigned short* __restrict__ Wf,
    int* __restrict__ wl)
{
    const int g = blockIdx.x * 256 + threadIdx.x;   // 0..131071
    const int e = g >> 11, k = g & 2047;
    const float w = W[g];                            // W[e][k], coalesced
    const _Float16 hi = (_Float16)w;                 // RNE
    const _Float16 lo = (_Float16)(w - (float)hi);   // exact residual, RNE
    const int n2 = e >> 5, lcol = e & 31;
    const int kc = k >> 4, khalf = (k >> 3) & 1, j = k & 7;
    const int lane = (khalf << 5) | lcol;
    Wf[((((0 * 2 + n2) * 128 + kc) << 6) + lane) * 8 + j] =
        __builtin_bit_cast(unsigned short, hi);
    Wf[((((1 * 2 + n2) * 128 + kc) << 6) + lane) * 8 + j] =
        __builtin_bit_cast(unsigned short, lo);
    if (g < WLOFF) wl[g] = 0;
}

// ---- kernel 1: f16-split MFMA GEMM + merge + routing + margin flag --------
// x staged through LDS in 512B-contiguous-per-row bursts (fixes the 64B@8KB-
// stride DRAM-locality wall): 16 mega-steps of K=128, double-buffered 32KB
// panels, per-lane pre-XOR-swizzled global source (T2/m173) so ds_read side
// is bank-spread. Wave (m,ks) computes chunk kc = 8*M + ks per mega-step.
// Counted WAITVM retires only own-wave stage ops; raw barriers publish.
// Accumulation order deterministic; error scale unchanged -> TAU unchanged.
__global__ __launch_bounds__(TPB1, 4) void gate_kernel(
    const float* __restrict__ x,
    const unsigned short* __restrict__ Wf,
    const float* __restrict__ b,
    const float* __restrict__ bias,
    float* __restrict__ out_w,
    float* __restrict__ out_i,
    int* __restrict__ wl)
{
    // union: [0,64K) = 2 x-panels (32KB each) during GEMM;
    // reused as sM (34944 B) + sS (16640 B) for merge/routing after.
    __shared__ __align__(16) char sLDS[65536];
    float* sM = (float*)sLDS;
    float (*sS)[65] = (float (*)[65])(sLDS + 34944);

    const int tid  = threadIdx.x;
    const int w    = tid >> 6;
    const int lane = tid & 63;
    const int m    = w >> 3;             // M-tile: tokens [32m, 32m+32)
    const int ks   = w & 7;              // K-sub: chunk ks of each mega-step
    const int tok0 = blockIdx.x * 64;
    const int l31  = lane & 31, lh = lane >> 5;

    const char* Wfb = (const char*)Wf;
    const char* xb  = (const char*)x;

    f32x16 acc0, acc1;
#pragma unroll
    for (int z = 0; z < 16; ++z) { acc0[z] = 0.f; acc1[z] = 0.f; }

    // stage x panel for mega-step Mn into buf (Mn&1): wave w stages rows
    // 4w..4w+3 (2 ops x 1KB, each op = 2 rows of 512B). Per-lane global src
    // is XOR-swizzled so LDS[r][g*16] = x[r][(g*16)^((r&7)<<4)].
#define STAGE_X(Mn) do {                                                      \
        char* dst_ = sLDS + (((Mn) & 1) ? 32768 : 0);                         \
        _Pragma("unroll")                                                     \
        for (int o_ = 0; o_ < 2; ++o_) {                                      \
            const int ra_  = 4 * w + 2 * o_;                                  \
            const int row_ = ra_ + lh;                                        \
            const int sw_  = (row_ & 7) << 4;                                 \
            const size_t src_ = (size_t)(tok0 + row_) * (DIM * 4)             \
                              + (size_t)(Mn) * 512 + ((l31 * 16) ^ sw_);      \
            gload_lds16(xb + src_, dst_ + ra_ * 512);                         \
        } } while (0)

    // ---- prologue: stage panel 0, drain, publish ----
    STAGE_X(0);
    WAITVM(0);
    __builtin_amdgcn_s_barrier();
    SB();

    for (int M = 0; M < 16; ++M) {
        // 1. issue next panel stage (2 vm ops)
        if (M < 15) STAGE_X(M + 1);
        SB();
        // 2. issue B-frag loads for this mega-step (4 vm ops, L2-hot)
        const int kc = 8 * M + ks;
        const f16x8 bh0 = *(const f16x8*)(Wfb + (size_t)((0 * 128 + kc) * 64 + lane) * 16);
        const f16x8 bh1 = *(const f16x8*)(Wfb + (size_t)((1 * 128 + kc) * 64 + lane) * 16);
        const f16x8 bl0 = *(const f16x8*)(Wfb + (size_t)((2 * 128 + kc) * 64 + lane) * 16);
        const f16x8 bl1 = *(const f16x8*)(Wfb + (size_t)((3 * 128 + kc) * 64 + lane) * 16);
        SB();
        // 3. retire stage(M) only: outstanding = stage(M)(<=2) + stage(M+1)(2)
        //    + B(4); vmcnt retires in order -> 6 leaves B + next stage in
        //    flight. Tail M=15: no stage(16) -> 4.
        if (M < 15) { WAITVM(6); } else { WAITVM(4); }
        SB();
        __builtin_amdgcn_s_barrier();   // panel M visible to all waves
        SB();

        // 4. compute chunk kc from LDS panel: A rows 32m+l31, k-run lh*8..
        {
            const char* pb = sLDS + ((M & 1) ? 32768 : 0)
                           + (32 * m + l31) * 512;
            const int sw   = ((32 * m + l31) & 7) << 4;
            const int colb = 64 * ks + 32 * lh;
            const float4 fa = *(const float4*)(pb + ((colb)      ^ sw));
            const float4 fb = *(const float4*)(pb + ((colb + 16) ^ sw));
            const float xv[8] = {fa.x, fa.y, fa.z, fa.w, fb.x, fb.y, fb.z, fb.w};
            f16x8 ah, al;
#pragma unroll
            for (int j = 0; j < 8; j += 2) {
                const auto h2 = __builtin_amdgcn_cvt_pkrtz(xv[j], xv[j + 1]);
                const auto l2 = __builtin_amdgcn_cvt_pkrtz(xv[j]     - (float)h2.x,
                                                           xv[j + 1] - (float)h2.y);
                ah[j] = h2.x; ah[j + 1] = h2.y;
                al[j] = l2.x; al[j + 1] = l2.y;
            }
            acc0 = __builtin_amdgcn_mfma_f32_32x32x16_f16(ah, bh0, acc0, 0, 0, 0);
            acc0 = __builtin_amdgcn_mfma_f32_32x32x16_f16(ah, bl0, acc0, 0, 0, 0);
            acc0 = __builtin_amdgcn_mfma_f32_32x32x16_f16(al, bh0, acc0, 0, 0, 0);
            acc1 = __builtin_amdgcn_mfma_f32_32x32x16_f16(ah, bh1, acc1, 0, 0, 0);
            acc1 = __builtin_amdgcn_mfma_f32_32x32x16_f16(ah, bl1, acc1, 0, 0, 0);
            acc1 = __builtin_amdgcn_mfma_f32_32x32x16_f16(al, bh1, acc1, 0, 0, 0);
        }
        SB();
        __builtin_amdgcn_s_barrier();   // all reads of panel M done before
        SB();                           // buf (M&1) is restaged at M+2
    }
#undef STAGE_X

    // ---- merge 8 K-slice partials (4 rounds x 16 tokens), fused sigmoid ----
    // C/D layout (m74/m101-verified): col = lane&31, row = (reg&3)+8*(reg>>2)+4*(lane>>5)
#pragma unroll
    for (int r = 0; r < 4; ++r) {
#pragma unroll
        for (int jj = 0; jj < 4; ++jj) {
            const int t16 = 8 * m + jj + 4 * lh;       // row-in-round
            sM[ks * SMSTR + t16 * 68 + l31]      = acc0[4 * r + jj];
            sM[ks * SMSTR + t16 * 68 + l31 + 32] = acc1[4 * r + jj];
        }
        __syncthreads();
        {
            const int t16 = tid >> 6;                  // 0..15
            const int e   = tid & 63;
            float sum = 0.f;
#pragma unroll
            for (int s = 0; s < NKS; ++s)
                sum += sM[s * SMSTR + t16 * 68 + e];   // ordered, deterministic
            const float logit = sum + b[e];
            const float wv = 1.0f / (1.0f + expf(-logit));
            const int t_blk = 32 * (t16 >> 3) + 8 * r + (t16 & 7);
            sS[t_blk][e] = wv + bias[e];
        }
        __syncthreads();
    }

    // ---- routing + margin flagging: thread t per token (r6-verified) ----
    if (tid < 64) {
        const int t = tid;

        float gs[NGRP];
#pragma unroll
        for (int g = 0; g < NGRP; ++g) {
            float m1 = NEG_INF, m2 = NEG_INF;
#pragma unroll
            for (int j = 0; j < GSIZE; ++j) {
                const float v = sS[t][g * GSIZE + j];
                if (v > m1) { m2 = m1; m1 = v; }
                else if (v > m2) { m2 = v; }
            }
            gs[g] = m1 + m2;
        }

        unsigned gmask = 0u;
        float g4val = NEG_INF;
        for (int rr = 0; rr < TOPKG; ++rr) {
            float best = NEG_INF; int bi = 0;
#pragma unroll
            for (int g = 0; g < NGRP; ++g) {
                const float v = ((gmask >> g) & 1u) ? NEG_INF : gs[g];
                if (v > best) { best = v; bi = g; }
            }
            gmask |= 1u << bi;
            g4val = best;
        }
        float m5 = NEG_INF;
#pragma unroll
        for (int g = 0; g < NGRP; ++g)
            if (!((gmask >> g) & 1u) && gs[g] > m5) m5 = gs[g];
        const float margin_g = g4val - m5;

        unsigned long long chosen = 0ull;
        const size_t obase = (size_t)(tok0 + t) * TOPK;
        float vals[TOPK + 1];
        for (int rr = 0; rr < TOPK + 1; ++rr) {
            float best = NEG_INF; int bi = 0;
            for (int e = 0; e < NEXP; ++e) {
                float v = ((gmask >> (e >> 3)) & 1u) ? sS[t][e] : 0.0f;
                if ((chosen >> e) & 1ull) v = NEG_INF;
                if (v > best) { best = v; bi = e; }
            }
            vals[rr] = best;
            if (rr < TOPK) {
                chosen |= 1ull << (unsigned)bi;
                out_w[obase + rr] = ((gmask >> (bi >> 3)) & 1u)
                                  ? (sS[t][bi] - bias[bi]) : 0.0f;
                out_i[obase + rr] = (float)bi;
            }
        }
        float margin_e = 1e30f;
#pragma unroll
        for (int rr = 0; rr < TOPK; ++rr) {
            const float d = vals[rr] - vals[rr + 1];
            if (d < margin_e) margin_e = d;
        }

        if (margin_g < TAU_G || margin_e < TAU_E) {
            const int slot = atomicAdd(wl, 1);
            wl[WLOFF + slot] = tok0 + t;
        }
    }
}

// ---------------- kernel 2: fp64 exact fixup, 1 token per iteration ---------
__global__ __launch_bounds__(256) void gate_fix_kernel(
    const float* __restrict__ x,
    const float* __restrict__ W,
    const float* __restrict__ b,
    const float* __restrict__ bias,
    float* __restrict__ out_w,
    float* __restrict__ out_i,
    const int* __restrict__ wl)
{
    const int count = wl[0];

    __shared__ __align__(16) float sX[DIM];
    __shared__ double sPart[NEXP][4];
    __shared__ float  sS2[NEXP], sW2[NEXP];

    const int tid = threadIdx.x;
    const int e   = tid >> 2;
    const int s   = tid & 3;

    for (int widx = blockIdx.x; widx < count; widx += (int)gridDim.x) {
        const int tok = wl[WLOFF + widx];

        const float4* xr = (const float4*)(x + (size_t)tok * DIM);
        ((float4*)sX)[tid]       = xr[tid];
        ((float4*)sX)[tid + 256] = xr[tid + 256];
        __syncthreads();

        const float4* Wr = (const float4*)(W + (size_t)e * DIM);
        double a0 = 0., a1 = 0., a2 = 0., a3 = 0.;
#pragma unroll 8
        for (int mm = 0; mm < DIM / 16; ++mm) {
            const int c = mm * 4 + s;
            const float4 wv = Wr[c];
            const float4 xv = ((const float4*)sX)[c];
            a0 = fma((double)xv.x, (double)wv.x, a0);
            a1 = fma((double)xv.y, (double)wv.y, a1);
            a2 = fma((double)xv.z, (double)wv.z, a2);
            a3 = fma((double)xv.w, (double)wv.w, a3);
        }
        sPart[e][s] = (a0 + a1) + (a2 + a3);
        __syncthreads();

        if (tid < NEXP) {
            const double logit = ((sPart[tid][0] + sPart[tid][1])
                                + (sPart[tid][2] + sPart[tid][3])) + (double)b[tid];
            const float wv = (float)(1.0 / (1.0 + exp(-logit)));
            sW2[tid] = wv;
            sS2[tid] = wv + bias[tid];
        }
        __syncthreads();

        if (tid == 0) {
            float gs[NGRP];
#pragma unroll
            for (int g = 0; g < NGRP; ++g) {
                float m1 = NEG_INF, m2 = NEG_INF;
#pragma unroll
                for (int j = 0; j < GSIZE; ++j) {
                    const float v = sS2[g * GSIZE + j];
                    if (v > m1) { m2 = m1; m1 = v; }
                    else if (v > m2) { m2 = v; }
                }
                gs[g] = m1 + m2;
            }
            unsigned gmask = 0u;
            for (int rr = 0; rr < TOPKG; ++rr) {
                float best = NEG_INF; int bi = 0;
#pragma unroll
                for (int g = 0; g < NGRP; ++g) {
                    const float v = ((gmask >> g) & 1u) ? NEG_INF : gs[g];
                    if (v > best) { best = v; bi = g; }
                }
                gmask |= 1u << bi;
            }
            unsigned long long chosen = 0ull;
            const size_t obase = (size_t)tok * TOPK;
            for (int rr = 0; rr < TOPK; ++rr) {
                float best = NEG_INF; int bi = 0;
                for (int e2 = 0; e2 < NEXP; ++e2) {
                    float v = ((gmask >> (e2 >> 3)) & 1u) ? sS2[e2] : 0.0f;
                    if ((chosen >> e2) & 1ull) v = NEG_INF;
                    if (v > best) { best = v; bi = e2; }
                }
                chosen |= 1ull << (unsigned)bi;
                out_w[obase + rr] = ((gmask >> (bi >> 3)) & 1u) ? sW2[bi] : 0.0f;
                out_i[obase + rr] = (float)bi;
            }
        }
        __syncthreads();
    }
}

extern "C" void kernel_launch(void* const* d_in, const int* in_sizes, int n_in,
                              void* d_out, int out_size, void* d_ws, size_t ws_size,
                              hipStream_t stream) {
    const float* x    = (const float*)d_in[0];
    const float* W    = (const float*)d_in[1];
    const float* b    = (const float*)d_in[2];
    const float* bias = (const float*)d_in[3];

    const int n = in_sizes[0] / DIM;   // 16384 tokens
    float* out_w = (float*)d_out;
    float* out_i = out_w + (size_t)n * TOPK;
    int*   wl    = (int*)d_ws;
    unsigned short* Wf = (unsigned short*)((char*)d_ws + WT_OFF);

    prep_kernel<<<dim3((NEXP * DIM) / 256), dim3(256), 0, stream>>>(W, Wf, wl);
    gate_kernel<<<dim3(n / 64), dim3(TPB1), 0, stream>>>(
        x, Wf, b, bias, out_w, out_i, wl);
    gate_fix_kernel<<<dim3(1024), dim3(256), 0, stream>>>(
        x, W, b, bias, out_w, out_i, wl);
}